// Round 15
// baseline (302.934 us; speedup 1.0000x reference)
//
#include <hip/hip_runtime.h>
#include <hip/hip_bf16.h>
#include <cstddef>
#include <cstdint>

typedef unsigned short u16;
typedef unsigned int uint32;
typedef __attribute__((ext_vector_type(8))) short bf16x8;
typedef __attribute__((ext_vector_type(4))) float f32x4;

#define SPATIAL 16384
#define TOTAL_M 131072

__device__ __forceinline__ u16 f2b(float f) {
  __hip_bfloat16 h = __float2bfloat16(f);
  return *reinterpret_cast<u16*>(&h);
}
__device__ __forceinline__ uint32 pk2(float a, float b) {
  return (uint32)f2b(a) | ((uint32)f2b(b) << 16);
}
__device__ __forceinline__ float blo(uint32 u) {
  union { uint32 u; float f; } c; c.u = u << 16; return c.f;
}
__device__ __forceinline__ float bhi(uint32 u) {
  union { uint32 u; float f; } c; c.u = u & 0xffff0000u; return c.f;
}

// async global->LDS, 16B per lane; lds base must be wave-uniform
__device__ __forceinline__ void gload_lds16(const u16* g, u16* l) {
  __builtin_amdgcn_global_load_lds(
      (const __attribute__((address_space(1))) void*)g,
      (__attribute__((address_space(3))) void*)l, 16, 0, 0);
}

// token base (element index into [131072][768]) for window gw, in-window token tt
template <int WS>
__device__ __forceinline__ size_t tok_base(int gw, int tt) {
  constexpr int WG = 128 / WS;
  constexpr int NWIN = WG * WG;
  int bb = gw / NWIN, rr = gw % NWIN;
  int gy = rr / WG, gx = rr % WG;
  int yy = gy * WS + tt / WS, xx = gx * WS + tt % WS;
  return (((size_t)bb * 128 + yy) * 128 + xx) * 768;
}

// ---------------- Kernel 0: prep -----------------------------------------
// blocks 0..2047: transpose+convert x [b][k][sp] fp32 -> xT [m][k] bf16
// blocks 2048..2063: convert qkv_w / proj_w fp32 -> bf16
__global__ __launch_bounds__(256) void prep(const float* __restrict__ x,
                                            const float* __restrict__ qw,
                                            const float* __restrict__ pw,
                                            u16* __restrict__ xT,
                                            u16* __restrict__ wq,
                                            u16* __restrict__ wp) {
  const int tid = threadIdx.x;
  const int bid = blockIdx.x;
  if (bid >= 2048) {
    const int t = (bid - 2048) * 256 + tid;
#pragma unroll
    for (int i = 0; i < 16; ++i) {
      const int e = i * 4096 + t;  // float4 index, 65536 total
      if (e < 49152) {
        float4 v = *(const float4*)&qw[(size_t)e * 4];
        ushort4 o;
        o.x = f2b(v.x); o.y = f2b(v.y); o.z = f2b(v.z); o.w = f2b(v.w);
        *(ushort4*)&wq[(size_t)e * 4] = o;
      } else {
        float4 v = *(const float4*)&pw[(size_t)(e - 49152) * 4];
        ushort4 o;
        o.x = f2b(v.x); o.y = f2b(v.y); o.z = f2b(v.z); o.w = f2b(v.w);
        *(ushort4*)&wp[(size_t)(e - 49152) * 4] = o;
      }
    }
    return;
  }
  __shared__ u16 Ts[64 * 256];
  const int b = bid >> 8;
  const int sp0 = (bid & 255) * 64;
#pragma unroll
  for (int it = 0; it < 16; ++it) {
    int e = it * 256 + tid;
    int k = e >> 4;
    int c4 = (e & 15) * 4;
    float4 v = *(const float4*)&x[(((size_t)(b * 256 + k)) << 14) + sp0 + c4];
    Ts[(c4 + 0) * 256 + (k ^ ((((c4 + 0)) & 31) << 3))] = f2b(v.x);
    Ts[(c4 + 1) * 256 + (k ^ ((((c4 + 1)) & 31) << 3))] = f2b(v.y);
    Ts[(c4 + 2) * 256 + (k ^ ((((c4 + 2)) & 31) << 3))] = f2b(v.z);
    Ts[(c4 + 3) * 256 + (k ^ ((((c4 + 3)) & 31) << 3))] = f2b(v.w);
  }
  __syncthreads();
#pragma unroll
  for (int it = 0; it < 8; ++it) {
    int e = it * 256 + tid;
    int sp = e >> 5;
    int kc = (e & 31) * 8;
    bf16x8 row = *(const bf16x8*)&Ts[sp * 256 + (kc ^ ((sp & 31) << 3))];
    *(bf16x8*)&xT[((size_t)(b * 16384 + sp0 + sp)) * 256 + kc] = row;
  }
}

// ---------------- Kernel 1: qkv GEMM — BK=32 counted-vmcnt dbuf ----------
// A = xT [131072][256] bf16, B = wq [768][256] bf16, C = qkv bf16.
// 8 K-steps (BK=32), double-buffered 32KB LDS total (4 blk/CU preserved),
// vmcnt(4) keeps next tile's loads in flight across each barrier: 6
// steady-state steps, each stage hidden under ~16 MFMA of the prior step.
// 4-chunk XOR swizzle (read = 4-way, 1.58x — acceptable).
__global__ __launch_bounds__(256) void gemm_qkv(const u16* __restrict__ xT,
                                                const u16* __restrict__ wq,
                                                u16* __restrict__ qkv) {
  __shared__ u16 As[2][128 * 32];
  __shared__ u16 Bs[2][128 * 32];
  const int tid = threadIdx.x;
  const int n0 = blockIdx.x * 128;
  const int m0 = blockIdx.y * 128;
  const int lane = tid & 63, w = tid >> 6;
  const int wr = w >> 1, wc = w & 1;
  const int fr = lane & 15, fk = lane >> 4;
  const int kxor = (fr & 3) << 3;   // read-side chunk XOR (u16 units)
  const int kcs = ((tid & 3) * 8) ^ (((tid >> 2) & 3) << 3);  // stage src off
  f32x4 acc[4][4] = {};

#define STAGE_Q(B, KT)                                                       \
  do {                                                                       \
    const int k0s = (KT)*32;                                                 \
    _Pragma("unroll") for (int it = 0; it < 2; ++it) {                       \
      int row = it * 64 + (tid >> 2);                                        \
      u16* la = &As[B][(it * 256 + (tid & 192)) * 8];                        \
      u16* lb = &Bs[B][(it * 256 + (tid & 192)) * 8];                        \
      gload_lds16(&xT[((size_t)(m0 + row) << 8) + k0s + kcs], la);           \
      gload_lds16(&wq[((size_t)(n0 + row) << 8) + k0s + kcs], lb);           \
    }                                                                        \
  } while (0)

#define COMP_Q(B)                                                            \
  do {                                                                       \
    bf16x8 af[4], bfr[4];                                                    \
    _Pragma("unroll") for (int i = 0; i < 4; ++i) {                          \
      af[i] = *(const bf16x8*)&As[B][(wr * 64 + i * 16 + fr) * 32 +          \
                                     ((fk << 3) ^ kxor)];                    \
      bfr[i] = *(const bf16x8*)&Bs[B][(wc * 64 + i * 16 + fr) * 32 +         \
                                      ((fk << 3) ^ kxor)];                   \
    }                                                                        \
    _Pragma("unroll") for (int i = 0; i < 4; ++i)                            \
        _Pragma("unroll") for (int j = 0; j < 4; ++j) acc[i][j] =            \
        __builtin_amdgcn_mfma_f32_16x16x32_bf16(bfr[j], af[i],               \
                                                acc[i][j], 0, 0, 0);         \
  } while (0)

#define PHASE_Q(WAITN)                                                       \
  asm volatile("s_waitcnt vmcnt(" #WAITN ")" ::: "memory");                  \
  __builtin_amdgcn_s_barrier();                                              \
  __builtin_amdgcn_sched_barrier(0)

#define PHASE_QEND()                                                         \
  __builtin_amdgcn_sched_barrier(0);                                         \
  __builtin_amdgcn_s_barrier()

  STAGE_Q(0, 0);
  STAGE_Q(1, 1);
  PHASE_Q(4); COMP_Q(0); PHASE_QEND(); STAGE_Q(0, 2);
  PHASE_Q(4); COMP_Q(1); PHASE_QEND(); STAGE_Q(1, 3);
  PHASE_Q(4); COMP_Q(0); PHASE_QEND(); STAGE_Q(0, 4);
  PHASE_Q(4); COMP_Q(1); PHASE_QEND(); STAGE_Q(1, 5);
  PHASE_Q(4); COMP_Q(0); PHASE_QEND(); STAGE_Q(0, 6);
  PHASE_Q(4); COMP_Q(1); PHASE_QEND(); STAGE_Q(1, 7);
  PHASE_Q(4); COMP_Q(0); PHASE_QEND();
  PHASE_Q(0); COMP_Q(1);
#undef STAGE_Q
#undef COMP_Q
#undef PHASE_Q
#undef PHASE_QEND

  // acc[i][j][r] = C[m = m0+wr*64+i*16+fr][n = n0+wc*64+j*16+fk*4+r]
#pragma unroll
  for (int i = 0; i < 4; ++i) {
    const size_t row = (size_t)(m0 + wr * 64 + i * 16 + fr) * 768;
#pragma unroll
    for (int j = 0; j < 4; ++j) {
      uint2 p;
      p.x = pk2(acc[i][j][0], acc[i][j][1]);
      p.y = pk2(acc[i][j][2], acc[i][j][3]);
      *(uint2*)&qkv[row + n0 + wc * 64 + j * 16 + fk * 4] = p;
    }
  }
}

// ---------------- small-window attention body (fp32 VALU, NT threads) ----
// Single QK pass, scores in registers. 16B/lane staging (8 lanes/token x
// 128B contiguous), 16B Q loads and O stores. Ks/Vs pad 72.
template <int WS, int NT>
__device__ __forceinline__ void win_attn_body(u16* __restrict__ qkv, int head,
                                              int bid, u16* __restrict__ smem) {
  constexpr int T = WS * WS;
  constexpr int G = NT / T;        // windows per block (tokens staged = NT)
  u16 (*Ks)[72] = (u16(*)[72])smem;
  u16 (*Vs)[72] = (u16(*)[72])(smem + NT * 72);
  const int tid = threadIdx.x;
  const int gw0 = bid * G;
  const int qoff = head * 64;

#pragma unroll
  for (int i = 0; i < 8; ++i) {
    int e8 = i * NT + tid;
    int tok = e8 >> 3;
    int d8 = (e8 & 7) * 8;
    size_t base = tok_base<WS>(gw0 + tok / T, tok % T);
    *(bf16x8*)&Ks[tok][d8] = *(const bf16x8*)&qkv[base + 256 + qoff + d8];
    *(bf16x8*)&Vs[tok][d8] = *(const bf16x8*)&qkv[base + 512 + qoff + d8];
  }
  __syncthreads();

  const int myw = tid / T;
  const int mytt = tid % T;
  const size_t mybase = tok_base<WS>(gw0 + myw, mytt);

  float q[64];
#pragma unroll
  for (int d8i = 0; d8i < 8; ++d8i) {
    union { bf16x8 v; uint32 u[4]; } U;
    U.v = *(const bf16x8*)&qkv[mybase + qoff + d8i * 8];
    q[d8i * 8 + 0] = blo(U.u[0]); q[d8i * 8 + 1] = bhi(U.u[0]);
    q[d8i * 8 + 2] = blo(U.u[1]); q[d8i * 8 + 3] = bhi(U.u[1]);
    q[d8i * 8 + 4] = blo(U.u[2]); q[d8i * 8 + 5] = bhi(U.u[2]);
    q[d8i * 8 + 6] = blo(U.u[3]); q[d8i * 8 + 7] = bhi(U.u[3]);
  }
  const int rbase = myw * T;

  // single QK pass, scores in registers
  float sarr[T];
  float mmax = -1e30f;
#pragma unroll
  for (int j = 0; j < T; ++j) {
    float s = 0.f;
#pragma unroll
    for (int d4 = 0; d4 < 16; ++d4) {
      uint2 k2 = *(const uint2*)&Ks[rbase + j][d4 * 4];
      s = fmaf(q[d4 * 4 + 0], blo(k2.x), s);
      s = fmaf(q[d4 * 4 + 1], bhi(k2.x), s);
      s = fmaf(q[d4 * 4 + 2], blo(k2.y), s);
      s = fmaf(q[d4 * 4 + 3], bhi(k2.y), s);
    }
    sarr[j] = s * 0.125f;
    mmax = fmaxf(mmax, sarr[j]);
  }
  float lsum = 0.f;
#pragma unroll
  for (int j = 0; j < T; ++j) {
    sarr[j] = __expf(sarr[j] - mmax);
    lsum += sarr[j];
  }
  const float inv = 1.f / lsum;

  float acc[64] = {};
#pragma unroll
  for (int j = 0; j < T; ++j) {
    const float p = sarr[j] * inv;
#pragma unroll
    for (int d4 = 0; d4 < 16; ++d4) {
      uint2 v2 = *(const uint2*)&Vs[rbase + j][d4 * 4];
      acc[d4 * 4 + 0] = fmaf(p, blo(v2.x), acc[d4 * 4 + 0]);
      acc[d4 * 4 + 1] = fmaf(p, bhi(v2.x), acc[d4 * 4 + 1]);
      acc[d4 * 4 + 2] = fmaf(p, blo(v2.y), acc[d4 * 4 + 2]);
      acc[d4 * 4 + 3] = fmaf(p, bhi(v2.y), acc[d4 * 4 + 3]);
    }
  }
#pragma unroll
  for (int d8i = 0; d8i < 8; ++d8i) {
    union { bf16x8 v; uint32 u[4]; } U;
    U.u[0] = pk2(acc[d8i * 8 + 0], acc[d8i * 8 + 1]);
    U.u[1] = pk2(acc[d8i * 8 + 2], acc[d8i * 8 + 3]);
    U.u[2] = pk2(acc[d8i * 8 + 4], acc[d8i * 8 + 5]);
    U.u[3] = pk2(acc[d8i * 8 + 6], acc[d8i * 8 + 7]);
    *(bf16x8*)&qkv[mybase + qoff + d8i * 8] = U.v;
  }
}

// ---------------- MFMA windowed attention body (ws=8/16, NW waves) -------
// G windows per block (TOK = G*T tokens staged). Full per-wave P buffer,
// one lgkmcnt wait per q-tile (R11-measured-best dataflow). 16B staging.
template <int WS, int NW, int G>
__device__ __forceinline__ void win_mfma_body(u16* __restrict__ qkv, int head,
                                              int bid, u16* __restrict__ smem) {
  constexpr int T = WS * WS;          // 64 or 256
  constexpr int TOK = G * T;          // tokens staged per block
  constexpr int KT = T / 16;          // 16-key tiles per window
  constexpr int KS = T / 32;          // PV K=32 steps
  constexpr int PL = T + 8;           // padded P row (u16)
  constexpr int VP = TOK + 8;         // padded Vt row (u16)
  constexpr int NT = NW * 64;         // threads
  constexpr int QPW = (G * T / 16) / NW;  // qtiles per wave
  u16* Ks = smem;                     // [TOK][72]
  u16* Vt = smem + TOK * 72;          // [64][VP]
  u16* Plds = Vt + 64 * VP;           // [NW*16][PL]
  const int tid = threadIdx.x;
  const int gw0 = bid * G;
  const int qoff = head * 64;

  // stage K (bf16 rows, 16B copies) and V (bf16 transposed)
#pragma unroll
  for (int it = 0; it < TOK * 8 / NT; ++it) {
    int e8 = it * NT + tid;
    int tok = e8 >> 3;
    int d8 = (e8 & 7) * 8;
    int win = tok / T, tt = tok % T;
    size_t base = tok_base<WS>(gw0 + win, tt);
    union { bf16x8 v; uint32 u[4]; } KK, VV;
    KK.v = *(const bf16x8*)&qkv[base + 256 + qoff + d8];
    VV.v = *(const bf16x8*)&qkv[base + 512 + qoff + d8];
    *(bf16x8*)&Ks[tok * 72 + d8] = KK.v;
#pragma unroll
    for (int z = 0; z < 4; ++z) {
      Vt[(d8 + 2 * z + 0) * VP + tok] = (u16)(VV.u[z] & 0xffffu);
      Vt[(d8 + 2 * z + 1) * VP + tok] = (u16)(VV.u[z] >> 16);
    }
  }
  __syncthreads();

  const int w = tid >> 6, lane = tid & 63;
  const int fr = lane & 15, fk = lane >> 4;
  u16* prow = &Plds[(w * 16 + fr) * PL];

  for (int qi = 0; qi < QPW; ++qi) {
    const int qg = w * QPW + qi;        // global q-tile
    const int win = qg / (T / 16);
    const int qt = qg % (T / 16);
    const int gw = gw0 + win;

    // Q fragments straight from global bf16
    const size_t qb = tok_base<WS>(gw, qt * 16 + fr) + qoff;
    bf16x8 qf[2];
#pragma unroll
    for (int ds = 0; ds < 2; ++ds)
      qf[ds] = *(const bf16x8*)&qkv[qb + ds * 32 + fk * 8];

    // S^T tiles
    f32x4 sv[KT];
#pragma unroll
    for (int kt = 0; kt < KT; ++kt) {
      const u16* krow = &Ks[(win * T + kt * 16 + fr) * 72];
      bf16x8 k0 = *(const bf16x8*)&krow[fk * 8];
      bf16x8 k1 = *(const bf16x8*)&krow[32 + fk * 8];
      f32x4 s = {};
      s = __builtin_amdgcn_mfma_f32_16x16x32_bf16(k0, qf[0], s, 0, 0, 0);
      s = __builtin_amdgcn_mfma_f32_16x16x32_bf16(k1, qf[1], s, 0, 0, 0);
      sv[kt] = s;
    }

    // softmax for query fr (keys spread over kt,r and the 4 fk-groups)
    float rmax = -3e38f;
#pragma unroll
    for (int kt = 0; kt < KT; ++kt)
#pragma unroll
      for (int r = 0; r < 4; ++r) rmax = fmaxf(rmax, sv[kt][r]);
    rmax = fmaxf(rmax, __shfl_xor(rmax, 16));
    rmax = fmaxf(rmax, __shfl_xor(rmax, 32));
    const float m = rmax * 0.125f;
    float l = 0.f;
#pragma unroll
    for (int kt = 0; kt < KT; ++kt)
#pragma unroll
      for (int r = 0; r < 4; ++r) {
        float ev = __expf(sv[kt][r] * 0.125f - m);
        sv[kt][r] = ev;
        l += ev;
      }
    l += __shfl_xor(l, 16);
    l += __shfl_xor(l, 32);
    const float linv = 1.f / l;

    // P -> LDS [query][key] bf16 (keys fk*4..fk*4+3 contiguous per kt)
#pragma unroll
    for (int kt = 0; kt < KT; ++kt) {
      uint2 pp;
      pp.x = pk2(sv[kt][0], sv[kt][1]);
      pp.y = pk2(sv[kt][2], sv[kt][3]);
      *(uint2*)&prow[kt * 16 + fk * 4] = pp;
    }
    __asm__ __volatile__("s_waitcnt lgkmcnt(0)" ::: "memory");
    __builtin_amdgcn_sched_barrier(0);

    // O = P . V
    f32x4 ov[4] = {};
#pragma unroll
    for (int ks = 0; ks < KS; ++ks) {
      bf16x8 pf = *(const bf16x8*)&prow[ks * 32 + fk * 8];
#pragma unroll
      for (int dt = 0; dt < 4; ++dt) {
        bf16x8 vf = *(const bf16x8*)&Vt[(dt * 16 + fr) * VP + win * T + ks * 32 + fk * 8];
        ov[dt] = __builtin_amdgcn_mfma_f32_16x16x32_bf16(pf, vf, ov[dt], 0, 0, 0);
      }
    }

    // scale by 1/l (routed from fr-space to fk*4+r-space) and store bf16
#pragma unroll
    for (int r = 0; r < 4; ++r) {
      float lr = __shfl(linv, fk * 4 + r);
      size_t ob = tok_base<WS>(gw, qt * 16 + fk * 4 + r) + qoff;
#pragma unroll
      for (int dt = 0; dt < 4; ++dt)
        qkv[ob + dt * 16 + fr] = f2b(ov[dt][r] * lr);
    }
  }
}

// ---------------- Kernel 2: ALL attention heads, one 512-thread launch ---
// 1280 blocks = 5 device waves at 1 block/CU (158.7KB LDS). LPT ordering:
// longest branch (ws16) dispatched FIRST so short blocks pack the tail.
__global__ __launch_bounds__(512) void attn_all(u16* __restrict__ qkv) {
  __shared__ u16 smem[79360];  // 158720 B (max: ws8 = 512*72+64*520+8*16*72)
  const int bid = blockIdx.x;
  if (bid < 512)
    win_mfma_body<16, 8, 1>(qkv, 3, bid, smem);
  else if (bid < 768)
    win_mfma_body<8, 8, 8>(qkv, 2, bid - 512, smem);
  else if (bid < 1024)
    win_attn_body<4, 512>(qkv, 1, bid - 768, smem);
  else
    win_attn_body<2, 512>(qkv, 0, bid - 1024, smem);
}

// ---------------- Kernel 3: proj GEMM — counted-vmcnt dbuf pipeline ------
__global__ __launch_bounds__(256) void gemm_proj(const u16* __restrict__ qkv,
                                                 const u16* __restrict__ wp,
                                                 const float* __restrict__ bias,
                                                 const float* __restrict__ x,
                                                 float* __restrict__ out) {
  __shared__ u16 As[2][128 * 64];
  __shared__ u16 Bs[2][128 * 64];
  const int tid = threadIdx.x;
  const int bid = blockIdx.x;
  const int logical = (bid & 7) * 256 + (bid >> 3);
  const int m0 = (logical >> 1) * 128;
  const int n0 = (logical & 1) * 128;
  const int lane = tid & 63, w = tid >> 6;
  const int wr = w >> 1, wc = w & 1;
  const int fr = lane & 15, fk = lane >> 4;
  const int frx = (fr & 7) << 3;
  const int kcs = ((tid & 7) * 8) ^ (((tid >> 3) & 7) << 3);
  const int srow = tid >> 3;
  const int b = m0 >> 14;
  f32x4 acc[4][4] = {};

#define STAGE_PRJ(B, KT)                                                     \
  do {                                                                       \
    const int k0s = (KT)*64;                                                 \
    _Pragma("unroll") for (int it = 0; it < 4; ++it) {                       \
      int row = it * 32 + srow;                                              \
      u16* la = &As[B][(it * 256 + (tid & 192)) * 8];                        \
      u16* lb = &Bs[B][(it * 256 + (tid & 192)) * 8];                        \
      gload_lds16(&qkv[(size_t)(m0 + row) * 768 + k0s + kcs], la);           \
      gload_lds16(&wp[((size_t)(n0 + row) << 8) + k0s + kcs], lb);           \
    }                                                                        \
  } while (0)

#define COMP_PRJ(B)                                                          \
  do {                                                                       \
    _Pragma("unroll") for (int kk = 0; kk < 2; ++kk) {                       \
      const int kb = (kk * 32 + fk * 8) ^ frx;                               \
      bf16x8 af[4], bfr[4];                                                  \
      _Pragma("unroll") for (int i = 0; i < 4; ++i) {                        \
        af[i] = *(const bf16x8*)&As[B][(wr * 64 + i * 16 + fr) * 64 + kb];   \
        bfr[i] = *(const bf16x8*)&Bs[B][(wc * 64 + i * 16 + fr) * 64 + kb];  \
      }                                                                      \
      _Pragma("unroll") for (int i = 0; i < 4; ++i)                          \
          _Pragma("unroll") for (int j = 0; j < 4; ++j) acc[i][j] =          \
          __builtin_amdgcn_mfma_f32_16x16x32_bf16(af[i], bfr[j],             \
                                                  acc[i][j], 0, 0, 0);       \
    }                                                                        \
  } while (0)

#define PHASE(WAITN)                                                         \
  asm volatile("s_waitcnt vmcnt(" #WAITN ")" ::: "memory");                  \
  __builtin_amdgcn_s_barrier();                                              \
  __builtin_amdgcn_sched_barrier(0)

#define PHASE_END()                                                         \
  __builtin_amdgcn_sched_barrier(0);                                         \
  __builtin_amdgcn_s_barrier()

  STAGE_PRJ(0, 0);
  STAGE_PRJ(1, 1);
  PHASE(8);
  COMP_PRJ(0);
  PHASE_END();
  STAGE_PRJ(0, 2);
  PHASE(8);
  COMP_PRJ(1);
  PHASE_END();
  STAGE_PRJ(1, 3);
  PHASE(8);
  COMP_PRJ(0);
  PHASE_END();
  PHASE(0);
  COMP_PRJ(1);
#undef STAGE_PRJ
#undef COMP_PRJ
#undef PHASE
#undef PHASE_END

  // acc[i][j][r]: m = m0+wr*64+i*16+fk*4+r, n = n0+wc*64+j*16+fr
#pragma unroll
  for (int i = 0; i < 4; ++i) {
    const int sp = (m0 & 16383) + wr * 64 + i * 16 + fk * 4;
#pragma unroll
    for (int j = 0; j < 4; ++j) {
      const int n = n0 + wc * 64 + j * 16 + fr;
      const size_t o = ((size_t)(b * 256 + n) << 14) + sp;
      const float4 r4 = *(const float4*)&x[o];
      const float bb = bias[n];
      float4 v = make_float4(acc[i][j][0] + bb + r4.x, acc[i][j][1] + bb + r4.y,
                             acc[i][j][2] + bb + r4.z, acc[i][j][3] + bb + r4.w);
      *(float4*)&out[o] = v;
    }
  }
}

extern "C" void kernel_launch(void* const* d_in, const int* in_sizes, int n_in,
                              void* d_out, int out_size, void* d_ws, size_t ws_size,
                              hipStream_t stream) {
  const float* x = (const float*)d_in[0];
  const float* qkv_w = (const float*)d_in[1];
  const float* proj_w = (const float*)d_in[2];
  const float* proj_b = (const float*)d_in[3];
  float* out = (float*)d_out;
  // workspace layout (bf16):
  //   qkv : 131072*768 u16 = 192 MiB
  //   xT  : 131072*256 u16 =  64 MiB
  //   wq  : 768*256 u16, wp : 256*256 u16
  u16* qkv = (u16*)d_ws;
  u16* xT = qkv + (size_t)131072 * 768;
  u16* wq = xT + (size_t)131072 * 256;
  u16* wp = wq + (size_t)768 * 256;

  prep<<<2064, 256, 0, stream>>>(x, qkv_w, proj_w, xT, wq, wp);
  gemm_qkv<<<dim3(6, 1024), 256, 0, stream>>>(xT, wq, qkv);
  attn_all<<<1280, 512, 0, stream>>>(qkv);        // all 4 heads, ws16 first
  gemm_proj<<<2048, 256, 0, stream>>>(qkv, wp, proj_b, x, out);
}

// Round 16
// 292.565 us; speedup vs baseline: 1.0354x; 1.0354x over previous
//
#include <hip/hip_runtime.h>
#include <hip/hip_bf16.h>
#include <cstddef>
#include <cstdint>

typedef unsigned short u16;
typedef unsigned int uint32;
typedef __attribute__((ext_vector_type(8))) short bf16x8;
typedef __attribute__((ext_vector_type(4))) float f32x4;

#define SPATIAL 16384
#define TOTAL_M 131072

__device__ __forceinline__ u16 f2b(float f) {
  __hip_bfloat16 h = __float2bfloat16(f);
  return *reinterpret_cast<u16*>(&h);
}
__device__ __forceinline__ uint32 pk2(float a, float b) {
  return (uint32)f2b(a) | ((uint32)f2b(b) << 16);
}
__device__ __forceinline__ float blo(uint32 u) {
  union { uint32 u; float f; } c; c.u = u << 16; return c.f;
}
__device__ __forceinline__ float bhi(uint32 u) {
  union { uint32 u; float f; } c; c.u = u & 0xffff0000u; return c.f;
}

// async global->LDS, 16B per lane; lds base must be wave-uniform
__device__ __forceinline__ void gload_lds16(const u16* g, u16* l) {
  __builtin_amdgcn_global_load_lds(
      (const __attribute__((address_space(1))) void*)g,
      (__attribute__((address_space(3))) void*)l, 16, 0, 0);
}

// token base (element index into [131072][768]) for window gw, in-window token tt
template <int WS>
__device__ __forceinline__ size_t tok_base(int gw, int tt) {
  constexpr int WG = 128 / WS;
  constexpr int NWIN = WG * WG;
  int bb = gw / NWIN, rr = gw % NWIN;
  int gy = rr / WG, gx = rr % WG;
  int yy = gy * WS + tt / WS, xx = gx * WS + tt % WS;
  return (((size_t)bb * 128 + yy) * 128 + xx) * 768;
}

// ---------------- Kernel 0: prep -----------------------------------------
// blocks 0..2047: transpose+convert x [b][k][sp] fp32 -> xT [m][k] bf16
// blocks 2048..2063: convert qkv_w / proj_w fp32 -> bf16
__global__ __launch_bounds__(256) void prep(const float* __restrict__ x,
                                            const float* __restrict__ qw,
                                            const float* __restrict__ pw,
                                            u16* __restrict__ xT,
                                            u16* __restrict__ wq,
                                            u16* __restrict__ wp) {
  const int tid = threadIdx.x;
  const int bid = blockIdx.x;
  if (bid >= 2048) {
    const int t = (bid - 2048) * 256 + tid;
#pragma unroll
    for (int i = 0; i < 16; ++i) {
      const int e = i * 4096 + t;  // float4 index, 65536 total
      if (e < 49152) {
        float4 v = *(const float4*)&qw[(size_t)e * 4];
        ushort4 o;
        o.x = f2b(v.x); o.y = f2b(v.y); o.z = f2b(v.z); o.w = f2b(v.w);
        *(ushort4*)&wq[(size_t)e * 4] = o;
      } else {
        float4 v = *(const float4*)&pw[(size_t)(e - 49152) * 4];
        ushort4 o;
        o.x = f2b(v.x); o.y = f2b(v.y); o.z = f2b(v.z); o.w = f2b(v.w);
        *(ushort4*)&wp[(size_t)(e - 49152) * 4] = o;
      }
    }
    return;
  }
  __shared__ u16 Ts[64 * 256];
  const int b = bid >> 8;
  const int sp0 = (bid & 255) * 64;
#pragma unroll
  for (int it = 0; it < 16; ++it) {
    int e = it * 256 + tid;
    int k = e >> 4;
    int c4 = (e & 15) * 4;
    float4 v = *(const float4*)&x[(((size_t)(b * 256 + k)) << 14) + sp0 + c4];
    Ts[(c4 + 0) * 256 + (k ^ ((((c4 + 0)) & 31) << 3))] = f2b(v.x);
    Ts[(c4 + 1) * 256 + (k ^ ((((c4 + 1)) & 31) << 3))] = f2b(v.y);
    Ts[(c4 + 2) * 256 + (k ^ ((((c4 + 2)) & 31) << 3))] = f2b(v.z);
    Ts[(c4 + 3) * 256 + (k ^ ((((c4 + 3)) & 31) << 3))] = f2b(v.w);
  }
  __syncthreads();
#pragma unroll
  for (int it = 0; it < 8; ++it) {
    int e = it * 256 + tid;
    int sp = e >> 5;
    int kc = (e & 31) * 8;
    bf16x8 row = *(const bf16x8*)&Ts[sp * 256 + (kc ^ ((sp & 31) << 3))];
    *(bf16x8*)&xT[((size_t)(b * 16384 + sp0 + sp)) * 256 + kc] = row;
  }
}

// ---------------- Kernel 1: qkv GEMM — R8 serial m97 structure (best) ----
// Seven structural variants measured (serial/dbuf/counted-vmcnt at BK=64,
// BK=32 counted, LDS-free, A-once, fused-transpose x2): serial BK=64
// single-buffer at 4 blk/CU wins. Tiny-K (256) leaves no pipeline room.
__global__ __launch_bounds__(256) void gemm_qkv(const u16* __restrict__ xT,
                                                const u16* __restrict__ wq,
                                                u16* __restrict__ qkv) {
  __shared__ u16 As[128 * 64];
  __shared__ u16 Bs[128 * 64];
  const int tid = threadIdx.x;
  const int n0 = blockIdx.x * 128;
  const int m0 = blockIdx.y * 128;
  const int lane = tid & 63, w = tid >> 6;
  const int wr = w >> 1, wc = w & 1;
  const int fr = lane & 15, fk = lane >> 4;
  const int frx = (fr & 7) << 3;
  f32x4 acc[4][4] = {};
  for (int kt = 0; kt < 4; ++kt) {
    const int k0 = kt * 64;
#pragma unroll
    for (int it = 0; it < 4; ++it) {
      int e = it * 256 + tid;
      int row = e >> 3;
      int kcs = ((e & 7) * 8) ^ ((row & 7) << 3);
      u16* la = &As[(it * 256 + (tid & 192)) * 8];
      u16* lb = &Bs[(it * 256 + (tid & 192)) * 8];
      gload_lds16(&xT[((size_t)(m0 + row) << 8) + k0 + kcs], la);
      gload_lds16(&wq[((size_t)(n0 + row) << 8) + k0 + kcs], lb);
    }
    __syncthreads();
#pragma unroll
    for (int kk = 0; kk < 2; ++kk) {
      const int kb = (kk * 32 + fk * 8) ^ frx;
      bf16x8 af[4], bfr[4];
#pragma unroll
      for (int i = 0; i < 4; ++i) {
        af[i] = *(const bf16x8*)&As[(wr * 64 + i * 16 + fr) * 64 + kb];
        bfr[i] = *(const bf16x8*)&Bs[(wc * 64 + i * 16 + fr) * 64 + kb];
      }
#pragma unroll
      for (int i = 0; i < 4; ++i)
#pragma unroll
        for (int j = 0; j < 4; ++j)
          acc[i][j] = __builtin_amdgcn_mfma_f32_16x16x32_bf16(bfr[j], af[i], acc[i][j], 0, 0, 0);
    }
    __syncthreads();
  }
  // acc[i][j][r] = C[m = m0+wr*64+i*16+fr][n = n0+wc*64+j*16+fk*4+r]
#pragma unroll
  for (int i = 0; i < 4; ++i) {
    const size_t row = (size_t)(m0 + wr * 64 + i * 16 + fr) * 768;
#pragma unroll
    for (int j = 0; j < 4; ++j) {
      uint2 p;
      p.x = pk2(acc[i][j][0], acc[i][j][1]);
      p.y = pk2(acc[i][j][2], acc[i][j][3]);
      *(uint2*)&qkv[row + n0 + wc * 64 + j * 16 + fk * 4] = p;
    }
  }
}

// ---------------- small-window attention body (fp32 VALU, NT threads) ----
// Single QK pass, scores in registers. 16B/lane staging (8 lanes/token x
// 128B contiguous), 16B Q loads and O stores. Ks/Vs pad 72.
template <int WS, int NT>
__device__ __forceinline__ void win_attn_body(u16* __restrict__ qkv, int head,
                                              int bid, u16* __restrict__ smem) {
  constexpr int T = WS * WS;
  constexpr int G = NT / T;        // windows per block (tokens staged = NT)
  u16 (*Ks)[72] = (u16(*)[72])smem;
  u16 (*Vs)[72] = (u16(*)[72])(smem + NT * 72);
  const int tid = threadIdx.x;
  const int gw0 = bid * G;
  const int qoff = head * 64;

#pragma unroll
  for (int i = 0; i < 8; ++i) {
    int e8 = i * NT + tid;
    int tok = e8 >> 3;
    int d8 = (e8 & 7) * 8;
    size_t base = tok_base<WS>(gw0 + tok / T, tok % T);
    *(bf16x8*)&Ks[tok][d8] = *(const bf16x8*)&qkv[base + 256 + qoff + d8];
    *(bf16x8*)&Vs[tok][d8] = *(const bf16x8*)&qkv[base + 512 + qoff + d8];
  }
  __syncthreads();

  const int myw = tid / T;
  const int mytt = tid % T;
  const size_t mybase = tok_base<WS>(gw0 + myw, mytt);

  float q[64];
#pragma unroll
  for (int d8i = 0; d8i < 8; ++d8i) {
    union { bf16x8 v; uint32 u[4]; } U;
    U.v = *(const bf16x8*)&qkv[mybase + qoff + d8i * 8];
    q[d8i * 8 + 0] = blo(U.u[0]); q[d8i * 8 + 1] = bhi(U.u[0]);
    q[d8i * 8 + 2] = blo(U.u[1]); q[d8i * 8 + 3] = bhi(U.u[1]);
    q[d8i * 8 + 4] = blo(U.u[2]); q[d8i * 8 + 5] = bhi(U.u[2]);
    q[d8i * 8 + 6] = blo(U.u[3]); q[d8i * 8 + 7] = bhi(U.u[3]);
  }
  const int rbase = myw * T;

  // single QK pass, scores in registers
  float sarr[T];
  float mmax = -1e30f;
#pragma unroll
  for (int j = 0; j < T; ++j) {
    float s = 0.f;
#pragma unroll
    for (int d4 = 0; d4 < 16; ++d4) {
      uint2 k2 = *(const uint2*)&Ks[rbase + j][d4 * 4];
      s = fmaf(q[d4 * 4 + 0], blo(k2.x), s);
      s = fmaf(q[d4 * 4 + 1], bhi(k2.x), s);
      s = fmaf(q[d4 * 4 + 2], blo(k2.y), s);
      s = fmaf(q[d4 * 4 + 3], bhi(k2.y), s);
    }
    sarr[j] = s * 0.125f;
    mmax = fmaxf(mmax, sarr[j]);
  }
  float lsum = 0.f;
#pragma unroll
  for (int j = 0; j < T; ++j) {
    sarr[j] = __expf(sarr[j] - mmax);
    lsum += sarr[j];
  }
  const float inv = 1.f / lsum;

  float acc[64] = {};
#pragma unroll
  for (int j = 0; j < T; ++j) {
    const float p = sarr[j] * inv;
#pragma unroll
    for (int d4 = 0; d4 < 16; ++d4) {
      uint2 v2 = *(const uint2*)&Vs[rbase + j][d4 * 4];
      acc[d4 * 4 + 0] = fmaf(p, blo(v2.x), acc[d4 * 4 + 0]);
      acc[d4 * 4 + 1] = fmaf(p, bhi(v2.x), acc[d4 * 4 + 1]);
      acc[d4 * 4 + 2] = fmaf(p, blo(v2.y), acc[d4 * 4 + 2]);
      acc[d4 * 4 + 3] = fmaf(p, bhi(v2.y), acc[d4 * 4 + 3]);
    }
  }
#pragma unroll
  for (int d8i = 0; d8i < 8; ++d8i) {
    union { bf16x8 v; uint32 u[4]; } U;
    U.u[0] = pk2(acc[d8i * 8 + 0], acc[d8i * 8 + 1]);
    U.u[1] = pk2(acc[d8i * 8 + 2], acc[d8i * 8 + 3]);
    U.u[2] = pk2(acc[d8i * 8 + 4], acc[d8i * 8 + 5]);
    U.u[3] = pk2(acc[d8i * 8 + 6], acc[d8i * 8 + 7]);
    *(bf16x8*)&qkv[mybase + qoff + d8i * 8] = U.v;
  }
}

// ---------------- MFMA windowed attention body (ws=8/16, NW waves) -------
// G windows per block (TOK = G*T tokens staged). Full per-wave P buffer,
// one lgkmcnt wait per q-tile (R11-measured-best dataflow). 16B staging.
template <int WS, int NW, int G>
__device__ __forceinline__ void win_mfma_body(u16* __restrict__ qkv, int head,
                                              int bid, u16* __restrict__ smem) {
  constexpr int T = WS * WS;          // 64 or 256
  constexpr int TOK = G * T;          // tokens staged per block
  constexpr int KT = T / 16;          // 16-key tiles per window
  constexpr int KS = T / 32;          // PV K=32 steps
  constexpr int PL = T + 8;           // padded P row (u16)
  constexpr int VP = TOK + 8;         // padded Vt row (u16)
  constexpr int NT = NW * 64;         // threads
  constexpr int QPW = (G * T / 16) / NW;  // qtiles per wave
  u16* Ks = smem;                     // [TOK][72]
  u16* Vt = smem + TOK * 72;          // [64][VP]
  u16* Plds = Vt + 64 * VP;           // [NW*16][PL]
  const int tid = threadIdx.x;
  const int gw0 = bid * G;
  const int qoff = head * 64;

  // stage K (bf16 rows, 16B copies) and V (bf16 transposed)
#pragma unroll
  for (int it = 0; it < TOK * 8 / NT; ++it) {
    int e8 = it * NT + tid;
    int tok = e8 >> 3;
    int d8 = (e8 & 7) * 8;
    int win = tok / T, tt = tok % T;
    size_t base = tok_base<WS>(gw0 + win, tt);
    union { bf16x8 v; uint32 u[4]; } KK, VV;
    KK.v = *(const bf16x8*)&qkv[base + 256 + qoff + d8];
    VV.v = *(const bf16x8*)&qkv[base + 512 + qoff + d8];
    *(bf16x8*)&Ks[tok * 72 + d8] = KK.v;
#pragma unroll
    for (int z = 0; z < 4; ++z) {
      Vt[(d8 + 2 * z + 0) * VP + tok] = (u16)(VV.u[z] & 0xffffu);
      Vt[(d8 + 2 * z + 1) * VP + tok] = (u16)(VV.u[z] >> 16);
    }
  }
  __syncthreads();

  const int w = tid >> 6, lane = tid & 63;
  const int fr = lane & 15, fk = lane >> 4;
  u16* prow = &Plds[(w * 16 + fr) * PL];

  for (int qi = 0; qi < QPW; ++qi) {
    const int qg = w * QPW + qi;        // global q-tile
    const int win = qg / (T / 16);
    const int qt = qg % (T / 16);
    const int gw = gw0 + win;

    // Q fragments straight from global bf16
    const size_t qb = tok_base<WS>(gw, qt * 16 + fr) + qoff;
    bf16x8 qf[2];
#pragma unroll
    for (int ds = 0; ds < 2; ++ds)
      qf[ds] = *(const bf16x8*)&qkv[qb + ds * 32 + fk * 8];

    // S^T tiles
    f32x4 sv[KT];
#pragma unroll
    for (int kt = 0; kt < KT; ++kt) {
      const u16* krow = &Ks[(win * T + kt * 16 + fr) * 72];
      bf16x8 k0 = *(const bf16x8*)&krow[fk * 8];
      bf16x8 k1 = *(const bf16x8*)&krow[32 + fk * 8];
      f32x4 s = {};
      s = __builtin_amdgcn_mfma_f32_16x16x32_bf16(k0, qf[0], s, 0, 0, 0);
      s = __builtin_amdgcn_mfma_f32_16x16x32_bf16(k1, qf[1], s, 0, 0, 0);
      sv[kt] = s;
    }

    // softmax for query fr (keys spread over kt,r and the 4 fk-groups)
    float rmax = -3e38f;
#pragma unroll
    for (int kt = 0; kt < KT; ++kt)
#pragma unroll
      for (int r = 0; r < 4; ++r) rmax = fmaxf(rmax, sv[kt][r]);
    rmax = fmaxf(rmax, __shfl_xor(rmax, 16));
    rmax = fmaxf(rmax, __shfl_xor(rmax, 32));
    const float m = rmax * 0.125f;
    float l = 0.f;
#pragma unroll
    for (int kt = 0; kt < KT; ++kt)
#pragma unroll
      for (int r = 0; r < 4; ++r) {
        float ev = __expf(sv[kt][r] * 0.125f - m);
        sv[kt][r] = ev;
        l += ev;
      }
    l += __shfl_xor(l, 16);
    l += __shfl_xor(l, 32);
    const float linv = 1.f / l;

    // P -> LDS [query][key] bf16 (keys fk*4..fk*4+3 contiguous per kt)
#pragma unroll
    for (int kt = 0; kt < KT; ++kt) {
      uint2 pp;
      pp.x = pk2(sv[kt][0], sv[kt][1]);
      pp.y = pk2(sv[kt][2], sv[kt][3]);
      *(uint2*)&prow[kt * 16 + fk * 4] = pp;
    }
    __asm__ __volatile__("s_waitcnt lgkmcnt(0)" ::: "memory");
    __builtin_amdgcn_sched_barrier(0);

    // O = P . V
    f32x4 ov[4] = {};
#pragma unroll
    for (int ks = 0; ks < KS; ++ks) {
      bf16x8 pf = *(const bf16x8*)&prow[ks * 32 + fk * 8];
#pragma unroll
      for (int dt = 0; dt < 4; ++dt) {
        bf16x8 vf = *(const bf16x8*)&Vt[(dt * 16 + fr) * VP + win * T + ks * 32 + fk * 8];
        ov[dt] = __builtin_amdgcn_mfma_f32_16x16x32_bf16(pf, vf, ov[dt], 0, 0, 0);
      }
    }

    // scale by 1/l (routed from fr-space to fk*4+r-space) and store bf16
#pragma unroll
    for (int r = 0; r < 4; ++r) {
      float lr = __shfl(linv, fk * 4 + r);
      size_t ob = tok_base<WS>(gw, qt * 16 + fk * 4 + r) + qoff;
#pragma unroll
      for (int dt = 0; dt < 4; ++dt)
        qkv[ob + dt * 16 + fr] = f2b(ov[dt][r] * lr);
    }
  }
}

// ---------------- Kernel 2: ALL attention heads, one 512-thread launch ---
// 1280 blocks = 5 device waves at 1 block/CU (158.7KB LDS). LPT ordering:
// longest branch (ws16) dispatched FIRST so short blocks pack the tail.
__global__ __launch_bounds__(512) void attn_all(u16* __restrict__ qkv) {
  __shared__ u16 smem[79360];  // 158720 B (max: ws8 = 512*72+64*520+8*16*72)
  const int bid = blockIdx.x;
  if (bid < 512)
    win_mfma_body<16, 8, 1>(qkv, 3, bid, smem);
  else if (bid < 768)
    win_mfma_body<8, 8, 8>(qkv, 2, bid - 512, smem);
  else if (bid < 1024)
    win_attn_body<4, 512>(qkv, 1, bid - 768, smem);
  else
    win_attn_body<2, 512>(qkv, 0, bid - 1024, smem);
}

// ---------------- Kernel 3: proj GEMM — counted-vmcnt dbuf pipeline ------
__global__ __launch_bounds__(256) void gemm_proj(const u16* __restrict__ qkv,
                                                 const u16* __restrict__ wp,
                                                 const float* __restrict__ bias,
                                                 const float* __restrict__ x,
                                                 float* __restrict__ out) {
  __shared__ u16 As[2][128 * 64];
  __shared__ u16 Bs[2][128 * 64];
  const int tid = threadIdx.x;
  const int bid = blockIdx.x;
  const int logical = (bid & 7) * 256 + (bid >> 3);
  const int m0 = (logical >> 1) * 128;
  const int n0 = (logical & 1) * 128;
  const int lane = tid & 63, w = tid >> 6;
  const int wr = w >> 1, wc = w & 1;
  const int fr = lane & 15, fk = lane >> 4;
  const int frx = (fr & 7) << 3;
  const int kcs = ((tid & 7) * 8) ^ (((tid >> 3) & 7) << 3);
  const int srow = tid >> 3;
  const int b = m0 >> 14;
  f32x4 acc[4][4] = {};

#define STAGE_PRJ(B, KT)                                                     \
  do {                                                                       \
    const int k0s = (KT)*64;                                                 \
    _Pragma("unroll") for (int it = 0; it < 4; ++it) {                       \
      int row = it * 32 + srow;                                              \
      u16* la = &As[B][(it * 256 + (tid & 192)) * 8];                        \
      u16* lb = &Bs[B][(it * 256 + (tid & 192)) * 8];                        \
      gload_lds16(&qkv[(size_t)(m0 + row) * 768 + k0s + kcs], la);           \
      gload_lds16(&wp[((size_t)(n0 + row) << 8) + k0s + kcs], lb);           \
    }                                                                        \
  } while (0)

#define COMP_PRJ(B)                                                          \
  do {                                                                       \
    _Pragma("unroll") for (int kk = 0; kk < 2; ++kk) {                       \
      const int kb = (kk * 32 + fk * 8) ^ frx;                               \
      bf16x8 af[4], bfr[4];                                                  \
      _Pragma("unroll") for (int i = 0; i < 4; ++i) {                        \
        af[i] = *(const bf16x8*)&As[B][(wr * 64 + i * 16 + fr) * 64 + kb];   \
        bfr[i] = *(const bf16x8*)&Bs[B][(wc * 64 + i * 16 + fr) * 64 + kb];  \
      }                                                                      \
      _Pragma("unroll") for (int i = 0; i < 4; ++i)                          \
          _Pragma("unroll") for (int j = 0; j < 4; ++j) acc[i][j] =          \
          __builtin_amdgcn_mfma_f32_16x16x32_bf16(af[i], bfr[j],             \
                                                  acc[i][j], 0, 0, 0);       \
    }                                                                        \
  } while (0)

#define PHASE(WAITN)                                                         \
  asm volatile("s_waitcnt vmcnt(" #WAITN ")" ::: "memory");                  \
  __builtin_amdgcn_s_barrier();                                              \
  __builtin_amdgcn_sched_barrier(0)

#define PHASE_END()                                                          \
  __builtin_amdgcn_sched_barrier(0);                                         \
  __builtin_amdgcn_s_barrier()

  STAGE_PRJ(0, 0);
  STAGE_PRJ(1, 1);
  PHASE(8);
  COMP_PRJ(0);
  PHASE_END();
  STAGE_PRJ(0, 2);
  PHASE(8);
  COMP_PRJ(1);
  PHASE_END();
  STAGE_PRJ(1, 3);
  PHASE(8);
  COMP_PRJ(0);
  PHASE_END();
  PHASE(0);
  COMP_PRJ(1);
#undef STAGE_PRJ
#undef COMP_PRJ
#undef PHASE
#undef PHASE_END

  // acc[i][j][r]: m = m0+wr*64+i*16+fk*4+r, n = n0+wc*64+j*16+fr
#pragma unroll
  for (int i = 0; i < 4; ++i) {
    const int sp = (m0 & 16383) + wr * 64 + i * 16 + fk * 4;
#pragma unroll
    for (int j = 0; j < 4; ++j) {
      const int n = n0 + wc * 64 + j * 16 + fr;
      const size_t o = ((size_t)(b * 256 + n) << 14) + sp;
      const float4 r4 = *(const float4*)&x[o];
      const float bb = bias[n];
      float4 v = make_float4(acc[i][j][0] + bb + r4.x, acc[i][j][1] + bb + r4.y,
                             acc[i][j][2] + bb + r4.z, acc[i][j][3] + bb + r4.w);
      *(float4*)&out[o] = v;
    }
  }
}

extern "C" void kernel_launch(void* const* d_in, const int* in_sizes, int n_in,
                              void* d_out, int out_size, void* d_ws, size_t ws_size,
                              hipStream_t stream) {
  const float* x = (const float*)d_in[0];
  const float* qkv_w = (const float*)d_in[1];
  const float* proj_w = (const float*)d_in[2];
  const float* proj_b = (const float*)d_in[3];
  float* out = (float*)d_out;
  // workspace layout (bf16):
  //   qkv : 131072*768 u16 = 192 MiB
  //   xT  : 131072*256 u16 =  64 MiB
  //   wq  : 768*256 u16, wp : 256*256 u16
  u16* qkv = (u16*)d_ws;
  u16* xT = qkv + (size_t)131072 * 768;
  u16* wq = xT + (size_t)131072 * 256;
  u16* wp = wq + (size_t)768 * 256;

  prep<<<2064, 256, 0, stream>>>(x, qkv_w, proj_w, xT, wq, wp);
  gemm_qkv<<<dim3(6, 1024), 256, 0, stream>>>(xT, wq, qkv);
  attn_all<<<1280, 512, 0, stream>>>(qkv);        // all 4 heads, ws16 first
  gemm_proj<<<2048, 256, 0, stream>>>(qkv, wp, proj_b, x, out);
}